// Round 6
// baseline (509.943 us; speedup 1.0000x reference)
//
#include <hip/hip_runtime.h>
#include <hip/hip_bf16.h>

typedef __bf16 bf16x8 __attribute__((ext_vector_type(8)));
typedef __bf16 bf16x4 __attribute__((ext_vector_type(4)));
typedef float  f32x4  __attribute__((ext_vector_type(4)));

// lgkm-only barrier: LDS ordering without draining vmcnt (trajectory stores
// are write-only, per-lane disjoint -> never need ordering). __syncthreads()
// would put every global store's completion on the per-step critical path.
#define BAR() asm volatile("s_waitcnt lgkmcnt(0)\n\ts_barrier" ::: "memory")

// tanh(x) = 1 - 2/(exp(2x)+1); native v_exp + v_rcp (no IEEE div expansion).
__device__ __forceinline__ float fast_tanh(float x) {
    float e = __expf(2.0f * x);
    float r = __builtin_amdgcn_rcpf(e + 1.0f);
    return __builtin_fmaf(-2.0f, r, 1.0f);
}

// Convert fp32 weights to bf16, TRANSPOSED to [n][k]: each lane's MFMA
// A-operand fragment (8 consecutive k at fixed n) is one contiguous 16B load.
__global__ void prep_weights(const float* __restrict__ W1,
                             const float* __restrict__ W2,
                             const float* __restrict__ W3,
                             __bf16* __restrict__ w1t,   // [256][64]
                             __bf16* __restrict__ w2t,   // [256][256]
                             __bf16* __restrict__ w3t) { // [64][256]
    int idx = blockIdx.x * blockDim.x + threadIdx.x;
    if (idx < 64 * 256) {                 // W1 [k=64][n=256] -> W1T[n][k]
        int n = idx >> 6, k = idx & 63;
        w1t[idx] = (__bf16)W1[k * 256 + n];
    }
    int i2 = idx - 64 * 256;
    if (i2 >= 0 && i2 < 256 * 256) {      // W2 [k=256][n=256] -> W2T[n][k]
        int n = i2 >> 8, k = i2 & 255;
        w2t[i2] = (__bf16)W2[k * 256 + n];
    }
    int i3 = idx - 64 * 256 - 256 * 256;  // W3 [k=256][n=64] -> W3T[n][k]
    if (i3 >= 0 && i3 < 64 * 256) {
        int n = i3 >> 8, k = i3 & 255;
        w3t[i3] = (__bf16)W3[k * 64 + n];
    }
}

// One block = 16 batch rows for ALL time steps. 256 threads = 4 waves
// (1 wave/SIMD). Evidence (R1/R3=289us@8w, R5=319us@16w): cost scales with
// barrier width, not per-wave work -> minimize waves, maximize per-wave ILP.
// Each wave: n-slice of 64 in GEMM1/2 (4 fragment columns), 16 in GEMM3.
// No wave idles in any phase. Weights live entirely in registers/AGPRs
// (~300 dwords/lane; gfx950 unified VGPR+AGPR file, MFMA reads AGPRs).
// x-state is register-resident (GEMM3 D-frag ownership); trajectory stores
// go straight from registers and are never waited on (lgkm-only barriers).
__global__ __launch_bounds__(256, 1)
void ode_kernel(const float* __restrict__ x0,
                const float* __restrict__ b1,
                const float* __restrict__ b2,
                const float* __restrict__ b3,
                const float* __restrict__ dt_scale,
                const int*   __restrict__ num_steps,
                const __bf16* __restrict__ w1t,
                const __bf16* __restrict__ w2t,
                const __bf16* __restrict__ w3t,
                float* __restrict__ out) {
    __shared__ __bf16 xb[16][72];    // bf16 state; 144B stride, 2-way max banks
    __shared__ __bf16 h1[16][264];   // 528B stride (33 granules) - proven layout
    __shared__ __bf16 h2[16][264];

    const int tid  = threadIdx.x;
    const int wave = tid >> 6;       // 0..3
    const int lane = tid & 63;
    const int q    = lane >> 4;      // quad
    const int c    = lane & 15;      // m (batch row) for B-frag & D; n-offset for A-frag
    const int row0 = blockIdx.x * 16;

    const float scale = dt_scale[0] * 0.01f;   // dt_scale * DT
    const int   nT    = num_steps[0];

    // ---- one-time weight fragment loads (A-operand layout, [n][k]) ----
    // G1/G2: this wave owns n in [wave*64, wave*64+64): 4 column-tiles.
    bf16x8 w1f[2][4];                 // [kt][nt]
    #pragma unroll
    for (int kt = 0; kt < 2; ++kt)
        #pragma unroll
        for (int nt = 0; nt < 4; ++nt) {
            int n = wave * 64 + nt * 16 + c;
            w1f[kt][nt] = *(const bf16x8*)(w1t + n * 64 + kt * 32 + q * 8);
        }
    bf16x8 w2f[8][4];                 // 128 dwords/lane -> AGPR territory
    #pragma unroll
    for (int kt = 0; kt < 8; ++kt)
        #pragma unroll
        for (int nt = 0; nt < 4; ++nt) {
            int n = wave * 64 + nt * 16 + c;
            w2f[kt][nt] = *(const bf16x8*)(w2t + n * 256 + kt * 32 + q * 8);
        }
    // G3: this wave owns n in [wave*16, wave*16+16).
    bf16x8 w3f[8];
    {
        int n = wave * 16 + c;
        #pragma unroll
        for (int kt = 0; kt < 8; ++kt)
            w3f[kt] = *(const bf16x8*)(w3t + n * 256 + kt * 32 + q * 8);
    }

    f32x4 b1v[4], b2v[4];
    #pragma unroll
    for (int nt = 0; nt < 4; ++nt) {
        b1v[nt] = *(const f32x4*)(b1 + wave * 64 + nt * 16 + q * 4);
        b2v[nt] = *(const f32x4*)(b2 + wave * 64 + nt * 16 + q * 4);
    }
    const f32x4 b3v = *(const f32x4*)(b3 + wave * 16 + q * 4);

    // ---- x-state in registers: lane(c,q) of wave w owns x[c][w*16+q*4..+3] ----
    f32x4 xv = *(const f32x4*)(x0 + (size_t)(row0 + c) * 64 + wave * 16 + q * 4);
    float* outp = out + (size_t)(row0 + c) * 201 * 64 + wave * 16 + q * 4;
    *(f32x4*)outp = xv;              // t = 0 trajectory slice
    outp += 64;
    {
        bf16x4 xbv;
        #pragma unroll
        for (int r = 0; r < 4; ++r) xbv[r] = (__bf16)xv[r];
        *(bf16x4*)(&xb[c][wave * 16 + q * 4]) = xbv;
    }
    BAR();

    for (int t = 0; t < nT; ++t) {
        // ---- GEMM1: h1 = tanh(x @ W1 + b1); 8 MFMA, 16 tanh per lane ----
        {
            bf16x8 xa[2];
            #pragma unroll
            for (int kt = 0; kt < 2; ++kt)
                xa[kt] = *(const bf16x8*)(&xb[c][kt * 32 + q * 8]);
            f32x4 acc[4] = {b1v[0], b1v[1], b1v[2], b1v[3]};
            #pragma unroll
            for (int kt = 0; kt < 2; ++kt)
                #pragma unroll
                for (int nt = 0; nt < 4; ++nt)
                    acc[nt] = __builtin_amdgcn_mfma_f32_16x16x32_bf16(w1f[kt][nt], xa[kt], acc[nt], 0, 0, 0);
            #pragma unroll
            for (int nt = 0; nt < 4; ++nt) {
                bf16x4 o;
                #pragma unroll
                for (int r = 0; r < 4; ++r) o[r] = (__bf16)fast_tanh(acc[nt][r]);
                *(bf16x4*)(&h1[c][wave * 64 + nt * 16 + q * 4]) = o;
            }
        }
        BAR();

        // ---- GEMM2: h2 = tanh(h1 @ W2 + b2); 32 MFMA as 8 independent
        //      4-deep chains; all 8 B-frags loaded upfront for ILP ----
        {
            bf16x8 f[8];
            #pragma unroll
            for (int kt = 0; kt < 8; ++kt)
                f[kt] = *(const bf16x8*)(&h1[c][kt * 32 + q * 8]);
            f32x4 acc[4]  = {b2v[0], b2v[1], b2v[2], b2v[3]};
            f32x4 accB[4] = {(f32x4){0,0,0,0}, (f32x4){0,0,0,0},
                             (f32x4){0,0,0,0}, (f32x4){0,0,0,0}};
            #pragma unroll
            for (int kt = 0; kt < 4; ++kt)
                #pragma unroll
                for (int nt = 0; nt < 4; ++nt) {
                    acc[nt]  = __builtin_amdgcn_mfma_f32_16x16x32_bf16(w2f[kt][nt],     f[kt],     acc[nt],  0, 0, 0);
                    accB[nt] = __builtin_amdgcn_mfma_f32_16x16x32_bf16(w2f[kt + 4][nt], f[kt + 4], accB[nt], 0, 0, 0);
                }
            #pragma unroll
            for (int nt = 0; nt < 4; ++nt) {
                f32x4 s = acc[nt] + accB[nt];
                bf16x4 o;
                #pragma unroll
                for (int r = 0; r < 4; ++r) o[r] = (__bf16)fast_tanh(s[r]);
                *(bf16x4*)(&h2[c][wave * 64 + nt * 16 + q * 4]) = o;
            }
        }
        BAR();

        // ---- GEMM3: dx = h2 @ W3 + b3; x += dx*scale in registers;
        //      write xb for next step + trajectory store (never waited on) ----
        {
            bf16x8 g[8];
            #pragma unroll
            for (int kt = 0; kt < 8; ++kt)
                g[kt] = *(const bf16x8*)(&h2[c][kt * 32 + q * 8]);
            f32x4 acc  = b3v;
            f32x4 accB = (f32x4){0, 0, 0, 0};
            #pragma unroll
            for (int kt = 0; kt < 4; ++kt) {
                acc  = __builtin_amdgcn_mfma_f32_16x16x32_bf16(w3f[kt],     g[kt],     acc,  0, 0, 0);
                accB = __builtin_amdgcn_mfma_f32_16x16x32_bf16(w3f[kt + 4], g[kt + 4], accB, 0, 0, 0);
            }
            acc += accB;
            xv += acc * scale;
            bf16x4 xbv;
            #pragma unroll
            for (int r = 0; r < 4; ++r) xbv[r] = (__bf16)xv[r];
            *(bf16x4*)(&xb[c][wave * 16 + q * 4]) = xbv;
            *(f32x4*)outp = xv;          // trajectory slice t+1
            outp += 64;
        }
        BAR();   // fences xb for next GEMM1
    }
}

extern "C" void kernel_launch(void* const* d_in, const int* in_sizes, int n_in,
                              void* d_out, int out_size, void* d_ws, size_t ws_size,
                              hipStream_t stream) {
    const float* x0 = (const float*)d_in[0];
    const float* W1 = (const float*)d_in[1];
    const float* b1 = (const float*)d_in[2];
    const float* W2 = (const float*)d_in[3];
    const float* b2 = (const float*)d_in[4];
    const float* W3 = (const float*)d_in[5];
    const float* b3 = (const float*)d_in[6];
    const float* dt = (const float*)d_in[7];
    const int*   ns = (const int*)d_in[8];

    __bf16* w1t = (__bf16*)d_ws;           // 16384 bf16
    __bf16* w2t = w1t + 64 * 256;          // 65536 bf16
    __bf16* w3t = w2t + 256 * 256;         // 16384 bf16

    prep_weights<<<384, 256, 0, stream>>>(W1, W2, W3, w1t, w2t, w3t);

    int rows = in_sizes[0] / 64;           // 4096
    ode_kernel<<<rows / 16, 256, 0, stream>>>(x0, b1, b2, b3, dt, ns,
                                              w1t, w2t, w3t, (float*)d_out);
}